// Round 7
// baseline (192.286 us; speedup 1.0000x reference)
//
#include <hip/hip_runtime.h>
#include <hip/hip_bf16.h>
#include <cstdint>

#define DEVI __device__ __forceinline__

typedef unsigned short u16;
typedef unsigned int u32;
typedef __attribute__((ext_vector_type(8))) short bf16x8;
typedef __attribute__((ext_vector_type(4))) float f32x4;
typedef __attribute__((ext_vector_type(4))) int i32x4;

DEVI u16 f2bf(float f) {
    union { float f; u32 u; } v; v.f = f;
    u32 r = v.u + 0x7fffu + ((v.u >> 16) & 1u);
    return (u16)(r >> 16);
}
DEVI u32 pk2(float a, float b) { return (u32)f2bf(a) | ((u32)f2bf(b) << 16); }

DEVI u32 cvtpk_bf16(float lo, float hi) {
    u32 r;
    asm("v_cvt_pk_bf16_f32 %0, %1, %2" : "=v"(r) : "v"(lo), "v"(hi));
    return r;
}

DEVI void gload_lds16(const void* g, void* l) {
    __builtin_amdgcn_global_load_lds(
        (const __attribute__((address_space(1))) u32*)(uintptr_t)g,
        (__attribute__((address_space(3))) u32*)(u32)(uintptr_t)l,
        16, 0, 0);
}

// ---------------- fused prep: build ctxb + cast 3 weight mats ----------------
__global__ __launch_bounds__(256) void prep_all(const float* __restrict__ x,
                                                const float* __restrict__ ctx,
                                                const float* __restrict__ Wq,
                                                const float* __restrict__ Wkv,
                                                const float* __restrict__ Wout,
                                                u16* __restrict__ ctxb,
                                                u16* __restrict__ wqb,
                                                u16* __restrict__ wkvb,
                                                u16* __restrict__ woutb) {
    int id = blockIdx.x;
    int tid = threadIdx.x;
    if (id < 4608) {                       // ctxb build
        int idx = id * 256 + tid;
        long e0 = (long)idx * 8;
        int b = (int)(e0 / (4608L * 512));
        long rem = e0 % (4608L * 512);
        int m = (int)(rem / 512);
        int d = (int)(rem % 512);
        const float* src = (m < 512) ? (x + ((long)b * 512 + m) * 512 + d)
                                     : (ctx + ((long)b * 4096 + (m - 512)) * 512 + d);
        float4 a = *(const float4*)src;
        float4 c = *(const float4*)(src + 4);
        uint4 u;
        u.x = pk2(a.x, a.y); u.y = pk2(a.z, a.w);
        u.z = pk2(c.x, c.y); u.w = pk2(c.z, c.w);
        *(uint4*)&ctxb[e0] = u;
        return;
    }
    const float* s;
    u16* d;
    int i;
    if (id < 4736)      { s = Wq;   d = wqb;   i = (id - 4608) * 256 + tid; }
    else if (id < 4992) { s = Wkv;  d = wkvb;  i = (id - 4736) * 256 + tid; }
    else                { s = Wout; d = woutb; i = (id - 4992) * 256 + tid; }
    const float4* s4 = (const float4*)s;
    float4 a = s4[i * 2], b = s4[i * 2 + 1];
    uint4 u;
    u.x = pk2(a.x, a.y); u.y = pk2(a.z, a.w);
    u.z = pk2(b.x, b.y); u.w = pk2(b.z, b.w);
    ((uint4*)d)[i] = u;
}

// ---------------- big GEMM: 128x256 tile, 8 waves, BK=64, dbuf ----------------
// blockIdx.y < 144: kv projection (A=ctxb rows, B=Wkv, K-half->kb, V-half->vtb^T)
// blockIdx.y >= 144: q projection (A=ctxb x-rows, B=Wq, C->qb), only bx<2 active.
__global__ __launch_bounds__(512) void gemm_kvq(const u16* __restrict__ ctxb,
                                                const u16* __restrict__ wkvb,
                                                const u16* __restrict__ wqb,
                                                u16* __restrict__ kb,
                                                u16* __restrict__ vtb,
                                                u16* __restrict__ qb) {
    const int K = 512;
    __shared__ u16 Asm[2][128 * 64];   // 16KB x2
    __shared__ u16 Bsm[2][256 * 64];   // 32KB x2
    int tid = threadIdx.x;
    int w = tid >> 6, l = tid & 63;
    int g = l >> 4, c = l & 15;
    int wr = w >> 2, wc = w & 3;       // 2x4 wave grid over 128x256

    const u16* B;
    u16* C;
    long r0, arow0;
    int rpb;
    bool isq = (blockIdx.y >= 144);
    if (isq) {
        if (blockIdx.x >= 2) return;
        r0 = (long)(blockIdx.y - 144) * 128;
        rpb = 512;
        B = wqb;
        C = qb;
    } else {
        r0 = (long)blockIdx.y * 128;
        rpb = 4608;
        B = wkvb;
        C = kb;
    }
    arow0 = (r0 / rpb) * (4608L * 512) + (r0 % rpb) * K;
    int n0 = blockIdx.x * 256;

    f32x4 acc[4][4];
#pragma unroll
    for (int i = 0; i < 4; i++)
#pragma unroll
        for (int j = 0; j < 4; j++) acc[i][j] = (f32x4){0.f, 0.f, 0.f, 0.f};

    int srow = l >> 3;
    int sch = l & 7;

    auto stage = [&](int kt, int bb) {
#pragma unroll
        for (int i = 0; i < 2; i++) {       // A: 16 chunks, 2/wave
            int c2 = w * 2 + i;
            int row = c2 * 8 + srow;
            int sc = sch ^ (row & 7);
            gload_lds16(ctxb + arow0 + (long)row * K + kt * 64 + sc * 8,
                        &Asm[bb][c2 * 512 + (l << 3)]);
        }
#pragma unroll
        for (int i = 0; i < 4; i++) {       // B: 32 chunks, 4/wave
            int c2 = w * 4 + i;
            int row = c2 * 8 + srow;
            int sc = sch ^ (row & 7);
            gload_lds16(B + (long)(n0 + row) * K + kt * 64 + sc * 8,
                        &Bsm[bb][c2 * 512 + (l << 3)]);
        }
    };

    stage(0, 0);
#pragma unroll 2
    for (int kt = 0; kt < 8; ++kt) {
        int pb = kt & 1;
        if (kt < 7) {
            stage(kt + 1, pb ^ 1);
            asm volatile("s_waitcnt vmcnt(6)" ::: "memory");
        } else {
            asm volatile("s_waitcnt vmcnt(0)" ::: "memory");
        }
        __builtin_amdgcn_s_barrier();
        __builtin_amdgcn_sched_barrier(0);
#pragma unroll
        for (int ks = 0; ks < 2; ++ks) {
            bf16x8 af[4], bfr[4];
#pragma unroll
            for (int mt = 0; mt < 4; ++mt) {
                int row = wr * 64 + mt * 16 + c;
                int ch = (ks * 4 + g) ^ (row & 7);
                af[mt] = *(const bf16x8*)&Asm[pb][row * 64 + ch * 8];
            }
#pragma unroll
            for (int nt = 0; nt < 4; ++nt) {
                int row = wc * 64 + nt * 16 + c;
                int ch = (ks * 4 + g) ^ (row & 7);
                bfr[nt] = *(const bf16x8*)&Bsm[pb][row * 64 + ch * 8];
            }
            __builtin_amdgcn_s_setprio(1);
#pragma unroll
            for (int mt = 0; mt < 4; ++mt)
#pragma unroll
                for (int nt = 0; nt < 4; ++nt)
                    acc[mt][nt] = __builtin_amdgcn_mfma_f32_16x16x32_bf16(
                        af[mt], bfr[nt], acc[mt][nt], 0, 0, 0);
            __builtin_amdgcn_s_setprio(0);
        }
        __builtin_amdgcn_s_barrier();
    }

    if (!isq && n0 >= 512) {               // V half -> VT[b,h,d,m] transposed
        int b2 = (int)(r0 / 4608);
        int mb = (int)(r0 - (long)b2 * 4608) + wr * 64;
#pragma unroll
        for (int mt = 0; mt < 4; ++mt) {
#pragma unroll
            for (int nt = 0; nt < 4; ++nt) {
                int colv = (n0 - 512) + wc * 64 + nt * 16 + c;
                int hh = colv >> 6, dd = colv & 63;
                long ob = ((long)(b2 * 8 + hh) * 64 + dd) * 4608 + mb + mt * 16 + g * 4;
                ushort4 pk;
                pk.x = f2bf(acc[mt][nt][0]);
                pk.y = f2bf(acc[mt][nt][1]);
                pk.z = f2bf(acc[mt][nt][2]);
                pk.w = f2bf(acc[mt][nt][3]);
                *(ushort4*)&vtb[ob] = pk;
            }
        }
        return;
    }
#pragma unroll
    for (int mt = 0; mt < 4; ++mt) {
#pragma unroll
        for (int r = 0; r < 4; ++r) {
            long row = r0 + wr * 64 + mt * 16 + g * 4 + r;
#pragma unroll
            for (int nt = 0; nt < 4; ++nt) {
                int col = n0 + wc * 64 + nt * 16 + c;
                C[row * 512 + col] = f2bf(acc[mt][nt][r]);
            }
        }
    }
}

// ---------------- out GEMM: 64x128 tile, 4 waves, f32 out ----------------
__global__ __launch_bounds__(256) void gemm_out(const u16* __restrict__ A,
                                                const u16* __restrict__ B,
                                                float* __restrict__ C) {
    const int K = 512;
    __shared__ u16 Asm[2][64 * 64];
    __shared__ u16 Bsm[2][128 * 64];
    int tid = threadIdx.x;
    int w = tid >> 6, l = tid & 63;
    int g = l >> 4, c = l & 15;
    int wr = w >> 1, wc = w & 1;       // 2x2 wave grid over 64x128
    long r0 = (long)blockIdx.y * 64;
    long arow0 = r0 * K;
    int n0 = blockIdx.x * 128;

    f32x4 acc[2][4];
#pragma unroll
    for (int i = 0; i < 2; i++)
#pragma unroll
        for (int j = 0; j < 4; j++) acc[i][j] = (f32x4){0.f, 0.f, 0.f, 0.f};

    int srow = l >> 3;
    int sch = l & 7;

    auto stage = [&](int kt, int bb) {
#pragma unroll
        for (int i = 0; i < 2; i++) {       // A: 8 chunks, 2/wave
            int c2 = w * 2 + i;
            int row = c2 * 8 + srow;
            int sc = sch ^ (row & 7);
            gload_lds16(A + arow0 + (long)row * K + kt * 64 + sc * 8,
                        &Asm[bb][c2 * 512 + (l << 3)]);
        }
#pragma unroll
        for (int i = 0; i < 4; i++) {       // B: 16 chunks, 4/wave
            int c2 = w * 4 + i;
            int row = c2 * 8 + srow;
            int sc = sch ^ (row & 7);
            gload_lds16(B + (long)(n0 + row) * K + kt * 64 + sc * 8,
                        &Bsm[bb][c2 * 512 + (l << 3)]);
        }
    };

    stage(0, 0);
#pragma unroll 2
    for (int kt = 0; kt < 8; ++kt) {
        int pb = kt & 1;
        if (kt < 7) {
            stage(kt + 1, pb ^ 1);
            asm volatile("s_waitcnt vmcnt(6)" ::: "memory");
        } else {
            asm volatile("s_waitcnt vmcnt(0)" ::: "memory");
        }
        __builtin_amdgcn_s_barrier();
        __builtin_amdgcn_sched_barrier(0);
#pragma unroll
        for (int ks = 0; ks < 2; ++ks) {
            bf16x8 af[2], bfr[4];
#pragma unroll
            for (int mt = 0; mt < 2; ++mt) {
                int row = wr * 32 + mt * 16 + c;
                int ch = (ks * 4 + g) ^ (row & 7);
                af[mt] = *(const bf16x8*)&Asm[pb][row * 64 + ch * 8];
            }
#pragma unroll
            for (int nt = 0; nt < 4; ++nt) {
                int row = wc * 64 + nt * 16 + c;
                int ch = (ks * 4 + g) ^ (row & 7);
                bfr[nt] = *(const bf16x8*)&Bsm[pb][row * 64 + ch * 8];
            }
#pragma unroll
            for (int mt = 0; mt < 2; ++mt)
#pragma unroll
                for (int nt = 0; nt < 4; ++nt)
                    acc[mt][nt] = __builtin_amdgcn_mfma_f32_16x16x32_bf16(
                        af[mt], bfr[nt], acc[mt][nt], 0, 0, 0);
        }
        __builtin_amdgcn_s_barrier();
    }
#pragma unroll
    for (int mt = 0; mt < 2; ++mt) {
#pragma unroll
        for (int r = 0; r < 4; ++r) {
            long row = r0 + wr * 32 + mt * 16 + g * 4 + r;
#pragma unroll
            for (int nt = 0; nt < 4; ++nt) {
                int col = n0 + wc * 64 + nt * 16 + c;
                C[row * 512 + col] = acc[mt][nt][r];
            }
        }
    }
}

// ---------------- flash attention, split-KV x8, swapped-operand ----------------
// 2048 blocks: 256 units (b,h,chunk) x 8 qblocks; 4 waves; 32KB LDS -> 5 blocks/CU.
// S^T = mfma(K,Q); softmax in-lane; P routed in-register (cvt_pk + bpermute);
// O^T = mfma(V,P). Per-lane lrun partial, reduced once in epilogue.
__global__ __launch_bounds__(256) void attn_kern(const u16* __restrict__ Q,
                                                 const u16* __restrict__ KB,
                                                 const u16* __restrict__ VT,
                                                 float* __restrict__ Op,
                                                 float2* __restrict__ ML) {
    __shared__ u16 Ksm[2][64 * 64];
    __shared__ u16 Vsm[2][64 * 64];
    int tid = threadIdx.x;
    int w = tid >> 6, l = tid & 63;
    int g = l >> 4, c = l & 15;
    int id = blockIdx.x;
    int u = (id & 7) | ((id >> 6) << 3);   // unit (b,h,chunk) 0..255
    int qi = (id >> 3) & 7;
    int p_ = u >> 3, chunk = u & 7;
    int b = p_ >> 3, h = p_ & 7;
    int qb0 = qi * 64;
    const int NT = 9;
    int it0 = chunk * NT;

    bf16x8 qf[2];   // B-operand fragment: Q^T[d=ks*32+g*8+j][q=c]
    {
        long qrow = (long)(b * 512 + qb0 + w * 16 + c);
#pragma unroll
        for (int ks = 0; ks < 2; ++ks)
            qf[ks] = *(const bf16x8*)&Q[qrow * 512 + h * 64 + ks * 32 + g * 8];
    }
    f32x4 o[4];     // O^T[d=nt*16+g*4+r][q=c]
#pragma unroll
    for (int nt = 0; nt < 4; nt++) o[nt] = (f32x4){0.f, 0.f, 0.f, 0.f};
    float mrun = -1e30f, lrun = 0.f;   // lrun = per-lane partial (16 positions)

    const float SCL = 0.125f * 1.44269504f;
    int srow8 = l >> 3, sch = l & 7;
    const long kbase = (long)b * 4608 * 512 + h * 64;
    const long vtbase = (long)(b * 8 + h) * 64 * 4608;

    int g2 = g << 1;
    int srcA = ((g2 & 3) << 4) | c;
    int srcB = (((g2 | 1) & 3) << 4) | c;
    bool hiT2 = (g >> 1) != 0;

    auto stage = [&](int it, int bb) {
#pragma unroll
        for (int i = 0; i < 2; i++) {
            int c2 = w * 2 + i;
            int row = c2 * 8 + srow8;
            int sc = sch ^ (row & 7);
            gload_lds16(KB + kbase + (long)(it * 64 + row) * 512 + sc * 8,
                        &Ksm[bb][c2 * 512 + (l << 3)]);
            gload_lds16(VT + vtbase + (long)row * 4608 + it * 64 + sc * 8,
                        &Vsm[bb][c2 * 512 + (l << 3)]);
        }
    };

    stage(it0, 0);
    for (int t = 0; t < NT; ++t) {
        int pbuf = t & 1;
        if (t + 1 < NT) {
            stage(it0 + t + 1, pbuf ^ 1);
            asm volatile("s_waitcnt vmcnt(4)" ::: "memory");
        } else {
            asm volatile("s_waitcnt vmcnt(0)" ::: "memory");
        }
        __builtin_amdgcn_s_barrier();      // tile t resident everywhere
        __builtin_amdgcn_sched_barrier(0);

        // S^T = K @ Q^T
        f32x4 st[4];
#pragma unroll
        for (int t2 = 0; t2 < 4; t2++) st[t2] = (f32x4){0.f, 0.f, 0.f, 0.f};
        __builtin_amdgcn_s_setprio(1);
#pragma unroll
        for (int ks = 0; ks < 2; ++ks) {
#pragma unroll
            for (int t2 = 0; t2 < 4; t2++) {
                int row = t2 * 16 + c;
                int ch = (ks * 4 + g) ^ (row & 7);
                bf16x8 kf = *(const bf16x8*)&Ksm[pbuf][row * 64 + ch * 8];
                st[t2] = __builtin_amdgcn_mfma_f32_16x16x32_bf16(kf, qf[ks], st[t2], 0, 0, 0);
            }
        }
        __builtin_amdgcn_s_setprio(0);

        float mx01 = fmaxf(fmaxf(st[0][0], st[0][1]), fmaxf(st[0][2], st[0][3]));
        float mx23 = fmaxf(fmaxf(st[1][0], st[1][1]), fmaxf(st[1][2], st[1][3]));
        float mx45 = fmaxf(fmaxf(st[2][0], st[2][1]), fmaxf(st[2][2], st[2][3]));
        float mx67 = fmaxf(fmaxf(st[3][0], st[3][1]), fmaxf(st[3][2], st[3][3]));
        float mx = fmaxf(fmaxf(mx01, mx23), fmaxf(mx45, mx67)) * SCL;
        mx = fmaxf(mx, __shfl_xor(mx, 16));
        mx = fmaxf(mx, __shfl_xor(mx, 32));

        bool need = mx > mrun + 8.f;       // defer-max (T13)
        if (__ballot(need)) {
            float mnew = fmaxf(mrun, mx);
            float rf = exp2f(mrun - mnew);
            mrun = mnew;
            lrun *= rf;
#pragma unroll
            for (int nt = 0; nt < 4; nt++)
#pragma unroll
                for (int r = 0; r < 4; r++) o[nt][r] *= rf;
        }
#pragma unroll
        for (int t2 = 0; t2 < 4; t2++)
#pragma unroll
            for (int r = 0; r < 4; r++) st[t2][r] = exp2f(st[t2][r] * SCL - mrun);

        lrun += ((st[0][0] + st[0][1]) + (st[0][2] + st[0][3]))
              + ((st[1][0] + st[1][1]) + (st[1][2] + st[1][3]))
              + ((st[2][0] + st[2][1]) + (st[2][2] + st[2][3]))
              + ((st[3][0] + st[3][1]) + (st[3][2] + st[3][3]));

        u32 u01[4], u23[4];
#pragma unroll
        for (int t2 = 0; t2 < 4; t2++) {
            u01[t2] = cvtpk_bf16(st[t2][0], st[t2][1]);
            u23[t2] = cvtpk_bf16(st[t2][2], st[t2][3]);
        }
        bf16x8 pbf[2];
#pragma unroll
        for (int ks = 0; ks < 2; ++ks) {
            u32 a0 = (u32)__shfl((int)u01[2 * ks], srcA);
            u32 a1 = (u32)__shfl((int)u01[2 * ks + 1], srcA);
            u32 b0 = (u32)__shfl((int)u23[2 * ks], srcA);
            u32 b1 = (u32)__shfl((int)u23[2 * ks + 1], srcA);
            u32 c0 = (u32)__shfl((int)u01[2 * ks], srcB);
            u32 c1 = (u32)__shfl((int)u01[2 * ks + 1], srcB);
            u32 d0 = (u32)__shfl((int)u23[2 * ks], srcB);
            u32 d1 = (u32)__shfl((int)u23[2 * ks + 1], srcB);
            i32x4 vv;
            vv[0] = (int)(hiT2 ? a1 : a0);
            vv[1] = (int)(hiT2 ? b1 : b0);
            vv[2] = (int)(hiT2 ? c1 : c0);
            vv[3] = (int)(hiT2 ? d1 : d0);
            pbf[ks] = __builtin_bit_cast(bf16x8, vv);
        }

        // O^T += V^T @ P^T
        __builtin_amdgcn_s_setprio(1);
#pragma unroll
        for (int ks = 0; ks < 2; ++ks) {
#pragma unroll
            for (int nt = 0; nt < 4; nt++) {
                int vrow = nt * 16 + c;
                int vch = (ks * 4 + g) ^ (vrow & 7);
                bf16x8 vb = *(const bf16x8*)&Vsm[pbuf][vrow * 64 + vch * 8];
                o[nt] = __builtin_amdgcn_mfma_f32_16x16x32_bf16(vb, pbf[ks], o[nt], 0, 0, 0);
            }
        }
        __builtin_amdgcn_s_setprio(0);
        __builtin_amdgcn_s_barrier();      // all waves done reading buf[pbuf]
    }

    // cross-lane reduce of the per-lane lrun partials (4 lanes per q-column)
    lrun += __shfl_xor(lrun, 16);
    lrun += __shfl_xor(lrun, 32);

    long prow = (long)(chunk * 32 + p_) * 512 + qb0 + w * 16;
#pragma unroll
    for (int nt = 0; nt < 4; nt++)
        *(f32x4*)&Op[(prow + c) * 64 + nt * 16 + g * 4] = o[nt];
    if (g == 0) ML[prow + c] = make_float2(mrun, lrun);
}

// ---------------- combine: merge 8 kv-chunk partials ----------------
__global__ __launch_bounds__(256) void attn_combine(const float* __restrict__ Op,
                                                    const float2* __restrict__ ML,
                                                    u16* __restrict__ O) {
    int tid = threadIdx.x;
    int w = tid >> 6, l = tid & 63;
    long rid = (long)blockIdx.x * 4 + w;   // 0..16383 : (p_, row)
    int p_ = (int)(rid >> 9);
    int row = (int)(rid & 511);
    int b = p_ >> 3, h = p_ & 7;
    float2 m[8];
#pragma unroll
    for (int cc = 0; cc < 8; cc++) m[cc] = ML[((long)(cc * 32 + p_) * 512 + row)];
    float mstar = fmaxf(fmaxf(fmaxf(m[0].x, m[1].x), fmaxf(m[2].x, m[3].x)),
                        fmaxf(fmaxf(m[4].x, m[5].x), fmaxf(m[6].x, m[7].x)));
    float wsum = 0.f, acc = 0.f;
#pragma unroll
    for (int cc = 0; cc < 8; cc++) {
        float wgt = exp2f(m[cc].x - mstar);
        wsum += wgt * m[cc].y;
        acc += wgt * Op[((long)(cc * 32 + p_) * 512 + row) * 64 + l];
    }
    O[((long)(b * 512 + row)) * 512 + h * 64 + l] = f2bf(acc / wsum);
}

// ---------------- launch ----------------

extern "C" void kernel_launch(void* const* d_in, const int* in_sizes, int n_in,
                              void* d_out, int out_size, void* d_ws, size_t ws_size,
                              hipStream_t stream) {
    const float* x = (const float*)d_in[0];
    const float* ctx = (const float*)d_in[1];
    const float* Wq = (const float*)d_in[2];
    const float* Wkv = (const float*)d_in[3];
    const float* Wout = (const float*)d_in[4];
    float* out = (float*)d_out;

    char* ws = (char*)d_ws;
    size_t off = 0;
    auto alloc = [&](size_t bytes) {
        size_t r = off;
        off += (bytes + 255) & ~(size_t)255;
        return r;
    };
    u16* ctxb = (u16*)(ws + alloc(4L * 4608 * 512 * 2));
    u16* wqb = (u16*)(ws + alloc(512L * 512 * 2));
    u16* wkvb = (u16*)(ws + alloc(1024L * 512 * 2));
    u16* woutb = (u16*)(ws + alloc(512L * 512 * 2));
    u16* qb = (u16*)(ws + alloc(2048L * 512 * 2));
    u16* kb = (u16*)(ws + alloc(4L * 4608 * 512 * 2));
    u16* vtb = (u16*)(ws + alloc(4L * 8 * 64 * 4608 * 2));
    u16* aob = (u16*)(ws + alloc(2048L * 512 * 2));
    float* opb = (float*)(ws + alloc(8L * 32 * 512 * 64 * 4));   // 33.6 MB
    float2* mlb = (float2*)(ws + alloc(8L * 32 * 512 * 8));      // 1 MB

    prep_all<<<dim3(5120), dim3(256), 0, stream>>>(x, ctx, Wq, Wkv, Wout,
                                                   ctxb, wqb, wkvb, woutb);
    // kv projection (rows 0..143) + q projection (rows 144..159, bx<2)
    gemm_kvq<<<dim3(4, 160), dim3(512), 0, stream>>>(ctxb, wkvb, wqb, kb, vtb, qb);
    attn_kern<<<dim3(2048), dim3(256), 0, stream>>>(qb, kb, vtb, opb, mlb);
    attn_combine<<<dim3(4096), dim3(256), 0, stream>>>(opb, mlb, aob);
    gemm_out<<<dim3(4, 32), dim3(256), 0, stream>>>(aob, woutb, out);
}

// Round 8
// 175.669 us; speedup vs baseline: 1.0946x; 1.0946x over previous
//
#include <hip/hip_runtime.h>
#include <hip/hip_bf16.h>
#include <cstdint>

#define DEVI __device__ __forceinline__

typedef unsigned short u16;
typedef unsigned int u32;
typedef __attribute__((ext_vector_type(8))) short bf16x8;
typedef __attribute__((ext_vector_type(4))) float f32x4;
typedef __attribute__((ext_vector_type(4))) int i32x4;

DEVI u16 f2bf(float f) {
    union { float f; u32 u; } v; v.f = f;
    u32 r = v.u + 0x7fffu + ((v.u >> 16) & 1u);
    return (u16)(r >> 16);
}
DEVI u32 pk2(float a, float b) { return (u32)f2bf(a) | ((u32)f2bf(b) << 16); }

DEVI u32 cvtpk_bf16(float lo, float hi) {
    u32 r;
    asm("v_cvt_pk_bf16_f32 %0, %1, %2" : "=v"(r) : "v"(lo), "v"(hi));
    return r;
}

DEVI void gload_lds16(const void* g, void* l) {
    __builtin_amdgcn_global_load_lds(
        (const __attribute__((address_space(1))) u32*)(uintptr_t)g,
        (__attribute__((address_space(3))) u32*)(u32)(uintptr_t)l,
        16, 0, 0);
}

// ---------------- fused prep: build ctxb + cast 3 weight mats ----------------
__global__ __launch_bounds__(256) void prep_all(const float* __restrict__ x,
                                                const float* __restrict__ ctx,
                                                const float* __restrict__ Wq,
                                                const float* __restrict__ Wkv,
                                                const float* __restrict__ Wout,
                                                u16* __restrict__ ctxb,
                                                u16* __restrict__ wqb,
                                                u16* __restrict__ wkvb,
                                                u16* __restrict__ woutb) {
    int id = blockIdx.x;
    int tid = threadIdx.x;
    if (id < 4608) {                       // ctxb build
        int idx = id * 256 + tid;
        long e0 = (long)idx * 8;
        int b = (int)(e0 / (4608L * 512));
        long rem = e0 % (4608L * 512);
        int m = (int)(rem / 512);
        int d = (int)(rem % 512);
        const float* src = (m < 512) ? (x + ((long)b * 512 + m) * 512 + d)
                                     : (ctx + ((long)b * 4096 + (m - 512)) * 512 + d);
        float4 a = *(const float4*)src;
        float4 c = *(const float4*)(src + 4);
        uint4 u;
        u.x = pk2(a.x, a.y); u.y = pk2(a.z, a.w);
        u.z = pk2(c.x, c.y); u.w = pk2(c.z, c.w);
        *(uint4*)&ctxb[e0] = u;
        return;
    }
    const float* s;
    u16* d;
    int i;
    if (id < 4736)      { s = Wq;   d = wqb;   i = (id - 4608) * 256 + tid; }
    else if (id < 4992) { s = Wkv;  d = wkvb;  i = (id - 4736) * 256 + tid; }
    else                { s = Wout; d = woutb; i = (id - 4992) * 256 + tid; }
    const float4* s4 = (const float4*)s;
    float4 a = s4[i * 2], b = s4[i * 2 + 1];
    uint4 u;
    u.x = pk2(a.x, a.y); u.y = pk2(a.z, a.w);
    u.z = pk2(b.x, b.y); u.w = pk2(b.z, b.w);
    ((uint4*)d)[i] = u;
}

// ---------------- big GEMM: 128x256 tile, 8 waves, BK=64, dbuf ----------------
// blockIdx.y < 144: kv projection (A=ctxb rows, B=Wkv, K-half->kb, V-half->vtb^T)
// blockIdx.y >= 144: q projection (A=ctxb x-rows, B=Wq, C->qb), only bx<2 active.
// V^T is written with per-64-block column permutation kv(p) so the attention
// kernel's P routing is shuffle-free: col = (mt>>1)*32 + g*8 + (mt&1)*4 + r.
__global__ __launch_bounds__(512) void gemm_kvq(const u16* __restrict__ ctxb,
                                                const u16* __restrict__ wkvb,
                                                const u16* __restrict__ wqb,
                                                u16* __restrict__ kb,
                                                u16* __restrict__ vtb,
                                                u16* __restrict__ qb) {
    const int K = 512;
    __shared__ u16 Asm[2][128 * 64];   // 16KB x2
    __shared__ u16 Bsm[2][256 * 64];   // 32KB x2
    int tid = threadIdx.x;
    int w = tid >> 6, l = tid & 63;
    int g = l >> 4, c = l & 15;
    int wr = w >> 2, wc = w & 3;       // 2x4 wave grid over 128x256

    const u16* B;
    u16* C;
    long r0, arow0;
    int rpb;
    bool isq = (blockIdx.y >= 144);
    if (isq) {
        if (blockIdx.x >= 2) return;
        r0 = (long)(blockIdx.y - 144) * 128;
        rpb = 512;
        B = wqb;
        C = qb;
    } else {
        r0 = (long)blockIdx.y * 128;
        rpb = 4608;
        B = wkvb;
        C = kb;
    }
    arow0 = (r0 / rpb) * (4608L * 512) + (r0 % rpb) * K;
    int n0 = blockIdx.x * 256;

    f32x4 acc[4][4];
#pragma unroll
    for (int i = 0; i < 4; i++)
#pragma unroll
        for (int j = 0; j < 4; j++) acc[i][j] = (f32x4){0.f, 0.f, 0.f, 0.f};

    int srow = l >> 3;
    int sch = l & 7;

    auto stage = [&](int kt, int bb) {
#pragma unroll
        for (int i = 0; i < 2; i++) {       // A: 16 chunks, 2/wave
            int c2 = w * 2 + i;
            int row = c2 * 8 + srow;
            int sc = sch ^ (row & 7);
            gload_lds16(ctxb + arow0 + (long)row * K + kt * 64 + sc * 8,
                        &Asm[bb][c2 * 512 + (l << 3)]);
        }
#pragma unroll
        for (int i = 0; i < 4; i++) {       // B: 32 chunks, 4/wave
            int c2 = w * 4 + i;
            int row = c2 * 8 + srow;
            int sc = sch ^ (row & 7);
            gload_lds16(B + (long)(n0 + row) * K + kt * 64 + sc * 8,
                        &Bsm[bb][c2 * 512 + (l << 3)]);
        }
    };

    stage(0, 0);
#pragma unroll 2
    for (int kt = 0; kt < 8; ++kt) {
        int pb = kt & 1;
        if (kt < 7) {
            stage(kt + 1, pb ^ 1);
            asm volatile("s_waitcnt vmcnt(6)" ::: "memory");
        } else {
            asm volatile("s_waitcnt vmcnt(0)" ::: "memory");
        }
        __builtin_amdgcn_s_barrier();
        __builtin_amdgcn_sched_barrier(0);
#pragma unroll
        for (int ks = 0; ks < 2; ++ks) {
            bf16x8 af[4], bfr[4];
#pragma unroll
            for (int mt = 0; mt < 4; ++mt) {
                int row = wr * 64 + mt * 16 + c;
                int ch = (ks * 4 + g) ^ (row & 7);
                af[mt] = *(const bf16x8*)&Asm[pb][row * 64 + ch * 8];
            }
#pragma unroll
            for (int nt = 0; nt < 4; ++nt) {
                int row = wc * 64 + nt * 16 + c;
                int ch = (ks * 4 + g) ^ (row & 7);
                bfr[nt] = *(const bf16x8*)&Bsm[pb][row * 64 + ch * 8];
            }
            __builtin_amdgcn_s_setprio(1);
#pragma unroll
            for (int mt = 0; mt < 4; ++mt)
#pragma unroll
                for (int nt = 0; nt < 4; ++nt)
                    acc[mt][nt] = __builtin_amdgcn_mfma_f32_16x16x32_bf16(
                        af[mt], bfr[nt], acc[mt][nt], 0, 0, 0);
            __builtin_amdgcn_s_setprio(0);
        }
        __builtin_amdgcn_s_barrier();
    }

    if (!isq && n0 >= 512) {               // V half -> VT[b,h,d,m'] permuted-transposed
        int b2 = (int)(r0 / 4608);
        int mb = (int)(r0 - (long)b2 * 4608) + wr * 64;   // multiple of 64
#pragma unroll
        for (int mt = 0; mt < 4; ++mt) {
#pragma unroll
            for (int nt = 0; nt < 4; ++nt) {
                int colv = (n0 - 512) + wc * 64 + nt * 16 + c;
                int hh = colv >> 6, dd = colv & 63;
                // within-tile position p = (mt>>1)*32 + g*8 + (mt&1)*4 + r
                long ob = ((long)(b2 * 8 + hh) * 64 + dd) * 4608 + mb
                        + (mt >> 1) * 32 + g * 8 + (mt & 1) * 4;
                ushort4 pk;
                pk.x = f2bf(acc[mt][nt][0]);
                pk.y = f2bf(acc[mt][nt][1]);
                pk.z = f2bf(acc[mt][nt][2]);
                pk.w = f2bf(acc[mt][nt][3]);
                *(ushort4*)&vtb[ob] = pk;
            }
        }
        return;
    }
#pragma unroll
    for (int mt = 0; mt < 4; ++mt) {
#pragma unroll
        for (int r = 0; r < 4; ++r) {
            long row = r0 + wr * 64 + mt * 16 + g * 4 + r;
#pragma unroll
            for (int nt = 0; nt < 4; ++nt) {
                int col = n0 + wc * 64 + nt * 16 + c;
                C[row * 512 + col] = f2bf(acc[mt][nt][r]);
            }
        }
    }
}

// ---------------- out GEMM: 64x128 tile, 4 waves, f32 out ----------------
__global__ __launch_bounds__(256) void gemm_out(const u16* __restrict__ A,
                                                const u16* __restrict__ B,
                                                float* __restrict__ C) {
    const int K = 512;
    __shared__ u16 Asm[2][64 * 64];
    __shared__ u16 Bsm[2][128 * 64];
    int tid = threadIdx.x;
    int w = tid >> 6, l = tid & 63;
    int g = l >> 4, c = l & 15;
    int wr = w >> 1, wc = w & 1;       // 2x2 wave grid over 64x128
    long r0 = (long)blockIdx.y * 64;
    long arow0 = r0 * K;
    int n0 = blockIdx.x * 128;

    f32x4 acc[2][4];
#pragma unroll
    for (int i = 0; i < 2; i++)
#pragma unroll
        for (int j = 0; j < 4; j++) acc[i][j] = (f32x4){0.f, 0.f, 0.f, 0.f};

    int srow = l >> 3;
    int sch = l & 7;

    auto stage = [&](int kt, int bb) {
#pragma unroll
        for (int i = 0; i < 2; i++) {       // A: 8 chunks, 2/wave
            int c2 = w * 2 + i;
            int row = c2 * 8 + srow;
            int sc = sch ^ (row & 7);
            gload_lds16(A + arow0 + (long)row * K + kt * 64 + sc * 8,
                        &Asm[bb][c2 * 512 + (l << 3)]);
        }
#pragma unroll
        for (int i = 0; i < 4; i++) {       // B: 16 chunks, 4/wave
            int c2 = w * 4 + i;
            int row = c2 * 8 + srow;
            int sc = sch ^ (row & 7);
            gload_lds16(B + (long)(n0 + row) * K + kt * 64 + sc * 8,
                        &Bsm[bb][c2 * 512 + (l << 3)]);
        }
    };

    stage(0, 0);
#pragma unroll 2
    for (int kt = 0; kt < 8; ++kt) {
        int pb = kt & 1;
        if (kt < 7) {
            stage(kt + 1, pb ^ 1);
            asm volatile("s_waitcnt vmcnt(6)" ::: "memory");
        } else {
            asm volatile("s_waitcnt vmcnt(0)" ::: "memory");
        }
        __builtin_amdgcn_s_barrier();
        __builtin_amdgcn_sched_barrier(0);
#pragma unroll
        for (int ks = 0; ks < 2; ++ks) {
            bf16x8 af[2], bfr[4];
#pragma unroll
            for (int mt = 0; mt < 2; ++mt) {
                int row = wr * 32 + mt * 16 + c;
                int ch = (ks * 4 + g) ^ (row & 7);
                af[mt] = *(const bf16x8*)&Asm[pb][row * 64 + ch * 8];
            }
#pragma unroll
            for (int nt = 0; nt < 4; ++nt) {
                int row = wc * 64 + nt * 16 + c;
                int ch = (ks * 4 + g) ^ (row & 7);
                bfr[nt] = *(const bf16x8*)&Bsm[pb][row * 64 + ch * 8];
            }
#pragma unroll
            for (int mt = 0; mt < 2; ++mt)
#pragma unroll
                for (int nt = 0; nt < 4; ++nt)
                    acc[mt][nt] = __builtin_amdgcn_mfma_f32_16x16x32_bf16(
                        af[mt], bfr[nt], acc[mt][nt], 0, 0, 0);
        }
        __builtin_amdgcn_s_barrier();
    }
#pragma unroll
    for (int mt = 0; mt < 2; ++mt) {
#pragma unroll
        for (int r = 0; r < 4; ++r) {
            long row = r0 + wr * 32 + mt * 16 + g * 4 + r;
#pragma unroll
            for (int nt = 0; nt < 4; ++nt) {
                int col = n0 + wc * 64 + nt * 16 + c;
                C[row * 512 + col] = acc[mt][nt][r];
            }
        }
    }
}

// ---------------- flash attention: 8 waves/block, split-KV x8, shuffle-free P ----------------
// 1024 blocks = 256 units (b,h,chunk) x 4 qblocks(128 q). 8 waves share one
// 32KB K/V dbuf (staging: 1 K + 1 V gload_lds per thread per tile, vmcnt(2)).
// S^T = mfma(K,Q) in-lane softmax; P regrouped IN-LANE to the PV B-operand
// (V^T global columns pre-permuted by gemm_kvq), zero cross-lane ops.
__global__ __launch_bounds__(512) void attn_kern(const u16* __restrict__ Q,
                                                 const u16* __restrict__ KB,
                                                 const u16* __restrict__ VT,
                                                 float* __restrict__ Op,
                                                 float2* __restrict__ ML) {
    __shared__ u16 Ksm[2][64 * 64];
    __shared__ u16 Vsm[2][64 * 64];
    int tid = threadIdx.x;
    int w = tid >> 6, l = tid & 63;
    int g = l >> 4, c = l & 15;
    int id = blockIdx.x;
    int u = (id & 7) | ((id >> 5) << 3);   // unit (b,h,chunk) 0..255
    int qi = (id >> 3) & 3;
    int p_ = u >> 3, chunk = u & 7;
    int b = p_ >> 3, h = p_ & 7;
    int qb0 = qi * 128;
    const int NT = 9;
    int it0 = chunk * NT;

    bf16x8 qf[2];   // B-operand fragment: Q^T[d=ks*32+g*8+j][q=c]
    {
        long qrow = (long)(b * 512 + qb0 + w * 16 + c);
#pragma unroll
        for (int ks = 0; ks < 2; ++ks)
            qf[ks] = *(const bf16x8*)&Q[qrow * 512 + h * 64 + ks * 32 + g * 8];
    }
    f32x4 o[4];     // O^T[d=nt*16+g*4+r][q=c]
#pragma unroll
    for (int nt = 0; nt < 4; nt++) o[nt] = (f32x4){0.f, 0.f, 0.f, 0.f};
    float mrun = -1e30f, lrun = 0.f;   // lrun = per-lane partial (16 positions)

    const float SCL = 0.125f * 1.44269504f;
    const long kbase = (long)b * 4608 * 512 + h * 64;
    const long vtbase = (long)(b * 8 + h) * 64 * 4608;

    int srow = tid >> 3;               // staging: this thread's tile row
    int ssc = (tid & 7) ^ (srow & 7);  // pre-swizzled source chunk

    auto stage = [&](int it, int bb) {
        gload_lds16(KB + kbase + (long)(it * 64 + srow) * 512 + ssc * 8,
                    &Ksm[bb][tid * 8]);
        gload_lds16(VT + vtbase + (long)srow * 4608 + it * 64 + ssc * 8,
                    &Vsm[bb][tid * 8]);
    };

    stage(it0, 0);
    for (int t = 0; t < NT; ++t) {
        int pbuf = t & 1;
        if (t + 1 < NT) {
            stage(it0 + t + 1, pbuf ^ 1);
            asm volatile("s_waitcnt vmcnt(2)" ::: "memory");
        } else {
            asm volatile("s_waitcnt vmcnt(0)" ::: "memory");
        }
        __builtin_amdgcn_s_barrier();      // tile t resident everywhere
        __builtin_amdgcn_sched_barrier(0);

        // S^T = K @ Q^T
        f32x4 st[4];
#pragma unroll
        for (int t2 = 0; t2 < 4; t2++) st[t2] = (f32x4){0.f, 0.f, 0.f, 0.f};
        __builtin_amdgcn_s_setprio(1);
#pragma unroll
        for (int ks = 0; ks < 2; ++ks) {
#pragma unroll
            for (int t2 = 0; t2 < 4; t2++) {
                int row = t2 * 16 + c;
                int ch = (ks * 4 + g) ^ (row & 7);
                bf16x8 kf = *(const bf16x8*)&Ksm[pbuf][row * 64 + ch * 8];
                st[t2] = __builtin_amdgcn_mfma_f32_16x16x32_bf16(kf, qf[ks], st[t2], 0, 0, 0);
            }
        }
        __builtin_amdgcn_s_setprio(0);

        float mx01 = fmaxf(fmaxf(st[0][0], st[0][1]), fmaxf(st[0][2], st[0][3]));
        float mx23 = fmaxf(fmaxf(st[1][0], st[1][1]), fmaxf(st[1][2], st[1][3]));
        float mx45 = fmaxf(fmaxf(st[2][0], st[2][1]), fmaxf(st[2][2], st[2][3]));
        float mx67 = fmaxf(fmaxf(st[3][0], st[3][1]), fmaxf(st[3][2], st[3][3]));
        float mx = fmaxf(fmaxf(mx01, mx23), fmaxf(mx45, mx67)) * SCL;
        mx = fmaxf(mx, __shfl_xor(mx, 16));
        mx = fmaxf(mx, __shfl_xor(mx, 32));

        bool need = mx > mrun + 8.f;       // defer-max (T13)
        if (__ballot(need)) {
            float mnew = fmaxf(mrun, mx);
            float rf = exp2f(mrun - mnew);
            mrun = mnew;
            lrun *= rf;
#pragma unroll
            for (int nt = 0; nt < 4; nt++)
#pragma unroll
                for (int r = 0; r < 4; r++) o[nt][r] *= rf;
        }
#pragma unroll
        for (int t2 = 0; t2 < 4; t2++)
#pragma unroll
            for (int r = 0; r < 4; r++) st[t2][r] = exp2f(st[t2][r] * SCL - mrun);

        lrun += ((st[0][0] + st[0][1]) + (st[0][2] + st[0][3]))
              + ((st[1][0] + st[1][1]) + (st[1][2] + st[1][3]))
              + ((st[2][0] + st[2][1]) + (st[2][2] + st[2][3]))
              + ((st[3][0] + st[3][1]) + (st[3][2] + st[3][3]));

        // shuffle-free P -> B-operand (V^T columns pre-permuted to match):
        // pbf[ks] slot j = st[2ks+(j>>2)][j&3]
        bf16x8 pbf[2];
#pragma unroll
        for (int ks = 0; ks < 2; ++ks) {
            i32x4 vv;
            vv[0] = (int)cvtpk_bf16(st[2 * ks][0], st[2 * ks][1]);
            vv[1] = (int)cvtpk_bf16(st[2 * ks][2], st[2 * ks][3]);
            vv[2] = (int)cvtpk_bf16(st[2 * ks + 1][0], st[2 * ks + 1][1]);
            vv[3] = (int)cvtpk_bf16(st[2 * ks + 1][2], st[2 * ks + 1][3]);
            pbf[ks] = __builtin_bit_cast(bf16x8, vv);
        }

        // O^T += V^T @ P^T
        __builtin_amdgcn_s_setprio(1);
#pragma unroll
        for (int ks = 0; ks < 2; ++ks) {
#pragma unroll
            for (int nt = 0; nt < 4; nt++) {
                int vrow = nt * 16 + c;
                int vch = (ks * 4 + g) ^ (vrow & 7);
                bf16x8 vb = *(const bf16x8*)&Vsm[pbuf][vrow * 64 + vch * 8];
                o[nt] = __builtin_amdgcn_mfma_f32_16x16x32_bf16(vb, pbf[ks], o[nt], 0, 0, 0);
            }
        }
        __builtin_amdgcn_s_setprio(0);
        __builtin_amdgcn_s_barrier();      // all waves done reading buf[pbuf]
    }

    // cross-lane reduce of the per-lane lrun partials (4 lanes per q-column)
    lrun += __shfl_xor(lrun, 16);
    lrun += __shfl_xor(lrun, 32);

    long prow = (long)(chunk * 32 + p_) * 512 + qb0 + w * 16;
#pragma unroll
    for (int nt = 0; nt < 4; nt++)
        *(f32x4*)&Op[(prow + c) * 64 + nt * 16 + g * 4] = o[nt];
    if (g == 0) ML[prow + c] = make_float2(mrun, lrun);
}

// ---------------- combine: merge 8 kv-chunk partials ----------------
__global__ __launch_bounds__(256) void attn_combine(const float* __restrict__ Op,
                                                    const float2* __restrict__ ML,
                                                    u16* __restrict__ O) {
    int tid = threadIdx.x;
    int w = tid >> 6, l = tid & 63;
    long rid = (long)blockIdx.x * 4 + w;   // 0..16383 : (p_, row)
    int p_ = (int)(rid >> 9);
    int row = (int)(rid & 511);
    int b = p_ >> 3, h = p_ & 7;
    float2 m[8];
#pragma unroll
    for (int cc = 0; cc < 8; cc++) m[cc] = ML[((long)(cc * 32 + p_) * 512 + row)];
    float mstar = fmaxf(fmaxf(fmaxf(m[0].x, m[1].x), fmaxf(m[2].x, m[3].x)),
                        fmaxf(fmaxf(m[4].x, m[5].x), fmaxf(m[6].x, m[7].x)));
    float wsum = 0.f, acc = 0.f;
#pragma unroll
    for (int cc = 0; cc < 8; cc++) {
        float wgt = exp2f(m[cc].x - mstar);
        wsum += wgt * m[cc].y;
        acc += wgt * Op[((long)(cc * 32 + p_) * 512 + row) * 64 + l];
    }
    O[((long)(b * 512 + row)) * 512 + h * 64 + l] = f2bf(acc / wsum);
}

// ---------------- launch ----------------

extern "C" void kernel_launch(void* const* d_in, const int* in_sizes, int n_in,
                              void* d_out, int out_size, void* d_ws, size_t ws_size,
                              hipStream_t stream) {
    const float* x = (const float*)d_in[0];
    const float* ctx = (const float*)d_in[1];
    const float* Wq = (const float*)d_in[2];
    const float* Wkv = (const float*)d_in[3];
    const float* Wout = (const float*)d_in[4];
    float* out = (float*)d_out;

    char* ws = (char*)d_ws;
    size_t off = 0;
    auto alloc = [&](size_t bytes) {
        size_t r = off;
        off += (bytes + 255) & ~(size_t)255;
        return r;
    };
    u16* ctxb = (u16*)(ws + alloc(4L * 4608 * 512 * 2));
    u16* wqb = (u16*)(ws + alloc(512L * 512 * 2));
    u16* wkvb = (u16*)(ws + alloc(1024L * 512 * 2));
    u16* woutb = (u16*)(ws + alloc(512L * 512 * 2));
    u16* qb = (u16*)(ws + alloc(2048L * 512 * 2));
    u16* kb = (u16*)(ws + alloc(4L * 4608 * 512 * 2));
    u16* vtb = (u16*)(ws + alloc(4L * 8 * 64 * 4608 * 2));
    u16* aob = (u16*)(ws + alloc(2048L * 512 * 2));
    float* opb = (float*)(ws + alloc(8L * 32 * 512 * 64 * 4));   // 33.6 MB
    float2* mlb = (float2*)(ws + alloc(8L * 32 * 512 * 8));      // 1 MB

    prep_all<<<dim3(5120), dim3(256), 0, stream>>>(x, ctx, Wq, Wkv, Wout,
                                                   ctxb, wqb, wkvb, woutb);
    // kv projection (rows 0..143) + q projection (rows 144..159, bx<2)
    gemm_kvq<<<dim3(4, 160), dim3(512), 0, stream>>>(ctxb, wkvb, wqb, kb, vtb, qb);
    attn_kern<<<dim3(1024), dim3(512), 0, stream>>>(qb, kb, vtb, opb, mlb);
    attn_combine<<<dim3(4096), dim3(256), 0, stream>>>(opb, mlb, aob);
    gemm_out<<<dim3(4, 32), dim3(256), 0, stream>>>(aob, woutb, out);
}

// Round 9
// 174.545 us; speedup vs baseline: 1.1016x; 1.0064x over previous
//
#include <hip/hip_runtime.h>
#include <hip/hip_bf16.h>
#include <cstdint>

#define DEVI __device__ __forceinline__

typedef unsigned short u16;
typedef unsigned int u32;
typedef __attribute__((ext_vector_type(8))) short bf16x8;
typedef __attribute__((ext_vector_type(4))) float f32x4;
typedef __attribute__((ext_vector_type(4))) int i32x4;

DEVI u16 f2bf(float f) {
    union { float f; u32 u; } v; v.f = f;
    u32 r = v.u + 0x7fffu + ((v.u >> 16) & 1u);
    return (u16)(r >> 16);
}
DEVI u32 pk2(float a, float b) { return (u32)f2bf(a) | ((u32)f2bf(b) << 16); }

DEVI u32 cvtpk_bf16(float lo, float hi) {
    u32 r;
    asm("v_cvt_pk_bf16_f32 %0, %1, %2" : "=v"(r) : "v"(lo), "v"(hi));
    return r;
}

DEVI void gload_lds16(const void* g, void* l) {
    __builtin_amdgcn_global_load_lds(
        (const __attribute__((address_space(1))) u32*)(uintptr_t)g,
        (__attribute__((address_space(3))) u32*)(u32)(uintptr_t)l,
        16, 0, 0);
}

// ---------------- fused prep: build ctxb + cast 3 weight mats ----------------
// Wq is pre-scaled by 0.125*log2(e) so attention scores land in exp2 domain.
__global__ __launch_bounds__(256) void prep_all(const float* __restrict__ x,
                                                const float* __restrict__ ctx,
                                                const float* __restrict__ Wq,
                                                const float* __restrict__ Wkv,
                                                const float* __restrict__ Wout,
                                                u16* __restrict__ ctxb,
                                                u16* __restrict__ wqb,
                                                u16* __restrict__ wkvb,
                                                u16* __restrict__ woutb) {
    int id = blockIdx.x;
    int tid = threadIdx.x;
    if (id < 4608) {                       // ctxb build
        int idx = id * 256 + tid;
        long e0 = (long)idx * 8;
        int b = (int)(e0 / (4608L * 512));
        long rem = e0 % (4608L * 512);
        int m = (int)(rem / 512);
        int d = (int)(rem % 512);
        const float* src = (m < 512) ? (x + ((long)b * 512 + m) * 512 + d)
                                     : (ctx + ((long)b * 4096 + (m - 512)) * 512 + d);
        float4 a = *(const float4*)src;
        float4 c = *(const float4*)(src + 4);
        uint4 u;
        u.x = pk2(a.x, a.y); u.y = pk2(a.z, a.w);
        u.z = pk2(c.x, c.y); u.w = pk2(c.z, c.w);
        *(uint4*)&ctxb[e0] = u;
        return;
    }
    const float* s;
    u16* d;
    int i;
    float scl = 1.0f;
    if (id < 4736)      { s = Wq;   d = wqb;   i = (id - 4608) * 256 + tid;
                          scl = 0.125f * 1.44269504f; }
    else if (id < 4992) { s = Wkv;  d = wkvb;  i = (id - 4736) * 256 + tid; }
    else                { s = Wout; d = woutb; i = (id - 4992) * 256 + tid; }
    const float4* s4 = (const float4*)s;
    float4 a = s4[i * 2], b = s4[i * 2 + 1];
    uint4 u;
    u.x = pk2(a.x * scl, a.y * scl); u.y = pk2(a.z * scl, a.w * scl);
    u.z = pk2(b.x * scl, b.y * scl); u.w = pk2(b.z * scl, b.w * scl);
    ((uint4*)d)[i] = u;
}

// ---------------- big GEMM: 128x128 tile, 8 waves (64x32 wave tile), BK=64, dbuf ----
// 64KB LDS -> 2 blocks/CU (latency hiding across resident blocks).
// by < 144: kv projection (K-half n0<512 -> kb; V-half -> vtb permuted-transposed)
// by >= 144: q projection (A = x-rows of ctxb, B=Wq, C=qb), bx<4 active.
// V^T per-64-block column permutation p = (mt>>1)*32 + g*8 + (mt&1)*4 + r.
__global__ __launch_bounds__(512) void gemm_kvq(const u16* __restrict__ ctxb,
                                                const u16* __restrict__ wkvb,
                                                const u16* __restrict__ wqb,
                                                u16* __restrict__ kb,
                                                u16* __restrict__ vtb,
                                                u16* __restrict__ qb) {
    const int K = 512;
    __shared__ u16 Asm[2][128 * 64];   // 16KB x2
    __shared__ u16 Bsm[2][128 * 64];   // 16KB x2
    int tid = threadIdx.x;
    int w = tid >> 6, l = tid & 63;
    int g = l >> 4, c = l & 15;
    int wr = w >> 2, wc = w & 3;       // 2x4 wave grid: wave tile 64x32

    const u16* B;
    u16* C;
    long r0, arow0;
    bool isq = (blockIdx.y >= 144);
    if (isq) {
        if (blockIdx.x >= 4) return;
        r0 = (long)(blockIdx.y - 144) * 128;
        arow0 = (r0 / 512) * (4608L * 512) + (r0 % 512) * K;
        B = wqb;
        C = qb;
    } else {
        r0 = (long)blockIdx.y * 128;
        arow0 = (r0 / 4608) * (4608L * 512) + (r0 % 4608) * K;
        B = wkvb;
        C = kb;
    }
    int n0 = blockIdx.x * 128;

    f32x4 acc[4][2];
#pragma unroll
    for (int i = 0; i < 4; i++)
#pragma unroll
        for (int j = 0; j < 2; j++) acc[i][j] = (f32x4){0.f, 0.f, 0.f, 0.f};

    int srow = l >> 3;
    int sch = l & 7;

    auto stage = [&](int kt, int bb) {
#pragma unroll
        for (int i = 0; i < 2; i++) {       // A: 16 chunks, 2/wave
            int c2 = w * 2 + i;
            int row = c2 * 8 + srow;
            int sc = sch ^ (row & 7);
            gload_lds16(ctxb + arow0 + (long)row * K + kt * 64 + sc * 8,
                        &Asm[bb][c2 * 512 + (l << 3)]);
            gload_lds16(B + (long)(n0 + row) * K + kt * 64 + sc * 8,
                        &Bsm[bb][c2 * 512 + (l << 3)]);
        }
    };

    stage(0, 0);
#pragma unroll 2
    for (int kt = 0; kt < 8; ++kt) {
        int pb = kt & 1;
        if (kt < 7) {
            stage(kt + 1, pb ^ 1);
            asm volatile("s_waitcnt vmcnt(4)" ::: "memory");
        } else {
            asm volatile("s_waitcnt vmcnt(0)" ::: "memory");
        }
        __builtin_amdgcn_s_barrier();
        __builtin_amdgcn_sched_barrier(0);
#pragma unroll
        for (int ks = 0; ks < 2; ++ks) {
            bf16x8 af[4], bfr[2];
#pragma unroll
            for (int mt = 0; mt < 4; ++mt) {
                int row = wr * 64 + mt * 16 + c;
                int ch = (ks * 4 + g) ^ (row & 7);
                af[mt] = *(const bf16x8*)&Asm[pb][row * 64 + ch * 8];
            }
#pragma unroll
            for (int nt = 0; nt < 2; ++nt) {
                int row = wc * 32 + nt * 16 + c;
                int ch = (ks * 4 + g) ^ (row & 7);
                bfr[nt] = *(const bf16x8*)&Bsm[pb][row * 64 + ch * 8];
            }
            __builtin_amdgcn_s_setprio(1);
#pragma unroll
            for (int mt = 0; mt < 4; ++mt)
#pragma unroll
                for (int nt = 0; nt < 2; ++nt)
                    acc[mt][nt] = __builtin_amdgcn_mfma_f32_16x16x32_bf16(
                        af[mt], bfr[nt], acc[mt][nt], 0, 0, 0);
            __builtin_amdgcn_s_setprio(0);
        }
        __builtin_amdgcn_s_barrier();
    }

    if (!isq && n0 >= 512) {               // V half -> VT[b,h,d,m'] permuted-transposed
        int b2 = (int)(r0 / 4608);
        int mb = (int)(r0 - (long)b2 * 4608) + wr * 64;   // multiple of 64
#pragma unroll
        for (int mt = 0; mt < 4; ++mt) {
#pragma unroll
            for (int nt = 0; nt < 2; ++nt) {
                int colv = (n0 - 512) + wc * 32 + nt * 16 + c;
                int hh = colv >> 6, dd = colv & 63;
                long ob = ((long)(b2 * 8 + hh) * 64 + dd) * 4608 + mb
                        + (mt >> 1) * 32 + g * 8 + (mt & 1) * 4;
                ushort4 pk;
                pk.x = f2bf(acc[mt][nt][0]);
                pk.y = f2bf(acc[mt][nt][1]);
                pk.z = f2bf(acc[mt][nt][2]);
                pk.w = f2bf(acc[mt][nt][3]);
                *(ushort4*)&vtb[ob] = pk;
            }
        }
        return;
    }
#pragma unroll
    for (int mt = 0; mt < 4; ++mt) {
#pragma unroll
        for (int r = 0; r < 4; ++r) {
            long row = r0 + wr * 64 + mt * 16 + g * 4 + r;
#pragma unroll
            for (int nt = 0; nt < 2; ++nt) {
                int col = n0 + wc * 32 + nt * 16 + c;
                C[row * 512 + col] = f2bf(acc[mt][nt][r]);
            }
        }
    }
}

// ---------------- out GEMM: 64x128 tile, 4 waves, f32 out ----------------
__global__ __launch_bounds__(256) void gemm_out(const u16* __restrict__ A,
                                                const u16* __restrict__ B,
                                                float* __restrict__ C) {
    const int K = 512;
    __shared__ u16 Asm[2][64 * 64];
    __shared__ u16 Bsm[2][128 * 64];
    int tid = threadIdx.x;
    int w = tid >> 6, l = tid & 63;
    int g = l >> 4, c = l & 15;
    int wr = w >> 1, wc = w & 1;       // 2x2 wave grid over 64x128
    long r0 = (long)blockIdx.y * 64;
    long arow0 = r0 * K;
    int n0 = blockIdx.x * 128;

    f32x4 acc[2][4];
#pragma unroll
    for (int i = 0; i < 2; i++)
#pragma unroll
        for (int j = 0; j < 4; j++) acc[i][j] = (f32x4){0.f, 0.f, 0.f, 0.f};

    int srow = l >> 3;
    int sch = l & 7;

    auto stage = [&](int kt, int bb) {
#pragma unroll
        for (int i = 0; i < 2; i++) {       // A: 8 chunks, 2/wave
            int c2 = w * 2 + i;
            int row = c2 * 8 + srow;
            int sc = sch ^ (row & 7);
            gload_lds16(A + arow0 + (long)row * K + kt * 64 + sc * 8,
                        &Asm[bb][c2 * 512 + (l << 3)]);
        }
#pragma unroll
        for (int i = 0; i < 4; i++) {       // B: 16 chunks, 4/wave
            int c2 = w * 4 + i;
            int row = c2 * 8 + srow;
            int sc = sch ^ (row & 7);
            gload_lds16(B + (long)(n0 + row) * K + kt * 64 + sc * 8,
                        &Bsm[bb][c2 * 512 + (l << 3)]);
        }
    };

    stage(0, 0);
#pragma unroll 2
    for (int kt = 0; kt < 8; ++kt) {
        int pb = kt & 1;
        if (kt < 7) {
            stage(kt + 1, pb ^ 1);
            asm volatile("s_waitcnt vmcnt(6)" ::: "memory");
        } else {
            asm volatile("s_waitcnt vmcnt(0)" ::: "memory");
        }
        __builtin_amdgcn_s_barrier();
        __builtin_amdgcn_sched_barrier(0);
#pragma unroll
        for (int ks = 0; ks < 2; ++ks) {
            bf16x8 af[2], bfr[4];
#pragma unroll
            for (int mt = 0; mt < 2; ++mt) {
                int row = wr * 32 + mt * 16 + c;
                int ch = (ks * 4 + g) ^ (row & 7);
                af[mt] = *(const bf16x8*)&Asm[pb][row * 64 + ch * 8];
            }
#pragma unroll
            for (int nt = 0; nt < 4; ++nt) {
                int row = wc * 64 + nt * 16 + c;
                int ch = (ks * 4 + g) ^ (row & 7);
                bfr[nt] = *(const bf16x8*)&Bsm[pb][row * 64 + ch * 8];
            }
#pragma unroll
            for (int mt = 0; mt < 2; ++mt)
#pragma unroll
                for (int nt = 0; nt < 4; ++nt)
                    acc[mt][nt] = __builtin_amdgcn_mfma_f32_16x16x32_bf16(
                        af[mt], bfr[nt], acc[mt][nt], 0, 0, 0);
        }
        __builtin_amdgcn_s_barrier();
    }
#pragma unroll
    for (int mt = 0; mt < 2; ++mt) {
#pragma unroll
        for (int r = 0; r < 4; ++r) {
            long row = r0 + wr * 32 + mt * 16 + g * 4 + r;
#pragma unroll
            for (int nt = 0; nt < 4; ++nt) {
                int col = n0 + wc * 64 + nt * 16 + c;
                C[row * 512 + col] = acc[mt][nt][r];
            }
        }
    }
}

// ---------------- flash attention: 8 waves/block, split-KV x8, shuffle-free P ----------------
// S^T = mfma(K,Q) (Q pre-scaled to exp2 domain); softmax in-lane; P regrouped
// in-lane to PV B-operand (V^T pre-permuted). Row-sum via ones-MFMA (idle pipe).
__global__ __launch_bounds__(512) void attn_kern(const u16* __restrict__ Q,
                                                 const u16* __restrict__ KB,
                                                 const u16* __restrict__ VT,
                                                 float* __restrict__ Op,
                                                 float2* __restrict__ ML) {
    __shared__ u16 Ksm[2][64 * 64];
    __shared__ u16 Vsm[2][64 * 64];
    int tid = threadIdx.x;
    int w = tid >> 6, l = tid & 63;
    int g = l >> 4, c = l & 15;
    int id = blockIdx.x;
    int u = (id & 7) | ((id >> 5) << 3);   // unit (b,h,chunk) 0..255
    int qi = (id >> 3) & 3;
    int p_ = u >> 3, chunk = u & 7;
    int b = p_ >> 3, h = p_ & 7;
    int qb0 = qi * 128;
    const int NT = 9;
    int it0 = chunk * NT;

    bf16x8 qf[2];   // B-operand fragment: Q^T[d=ks*32+g*8+j][q=c]
    {
        long qrow = (long)(b * 512 + qb0 + w * 16 + c);
#pragma unroll
        for (int ks = 0; ks < 2; ++ks)
            qf[ks] = *(const bf16x8*)&Q[qrow * 512 + h * 64 + ks * 32 + g * 8];
    }
    bf16x8 onesf;
#pragma unroll
    for (int e = 0; e < 8; e++) onesf[e] = (short)0x3F80;  // bf16 1.0

    f32x4 o[4];     // O^T[d=nt*16+g*4+r][q=c]
#pragma unroll
    for (int nt = 0; nt < 4; nt++) o[nt] = (f32x4){0.f, 0.f, 0.f, 0.f};
    f32x4 ls = (f32x4){0.f, 0.f, 0.f, 0.f};   // row-sum accum (all 4 entries equal)
    float mrun = -1e30f;

    const long kbase = (long)b * 4608 * 512 + h * 64;
    const long vtbase = (long)(b * 8 + h) * 64 * 4608;

    int srow = tid >> 3;               // staging: this thread's tile row
    int ssc = (tid & 7) ^ (srow & 7);  // pre-swizzled source chunk

    auto stage = [&](int it, int bb) {
        gload_lds16(KB + kbase + (long)(it * 64 + srow) * 512 + ssc * 8,
                    &Ksm[bb][tid * 8]);
        gload_lds16(VT + vtbase + (long)srow * 4608 + it * 64 + ssc * 8,
                    &Vsm[bb][tid * 8]);
    };

    stage(it0, 0);
    for (int t = 0; t < NT; ++t) {
        int pbuf = t & 1;
        if (t + 1 < NT) {
            stage(it0 + t + 1, pbuf ^ 1);
            asm volatile("s_waitcnt vmcnt(2)" ::: "memory");
        } else {
            asm volatile("s_waitcnt vmcnt(0)" ::: "memory");
        }
        __builtin_amdgcn_s_barrier();      // tile t resident everywhere
        __builtin_amdgcn_sched_barrier(0);

        // S^T = K @ Q^T (already in exp2 domain)
        f32x4 st[4];
#pragma unroll
        for (int t2 = 0; t2 < 4; t2++) st[t2] = (f32x4){0.f, 0.f, 0.f, 0.f};
        __builtin_amdgcn_s_setprio(1);
#pragma unroll
        for (int ks = 0; ks < 2; ++ks) {
#pragma unroll
            for (int t2 = 0; t2 < 4; t2++) {
                int row = t2 * 16 + c;
                int ch = (ks * 4 + g) ^ (row & 7);
                bf16x8 kf = *(const bf16x8*)&Ksm[pbuf][row * 64 + ch * 8];
                st[t2] = __builtin_amdgcn_mfma_f32_16x16x32_bf16(kf, qf[ks], st[t2], 0, 0, 0);
            }
        }
        __builtin_amdgcn_s_setprio(0);

        float mx01 = fmaxf(fmaxf(st[0][0], st[0][1]), fmaxf(st[0][2], st[0][3]));
        float mx23 = fmaxf(fmaxf(st[1][0], st[1][1]), fmaxf(st[1][2], st[1][3]));
        float mx45 = fmaxf(fmaxf(st[2][0], st[2][1]), fmaxf(st[2][2], st[2][3]));
        float mx67 = fmaxf(fmaxf(st[3][0], st[3][1]), fmaxf(st[3][2], st[3][3]));
        float mx = fmaxf(fmaxf(mx01, mx23), fmaxf(mx45, mx67));
        mx = fmaxf(mx, __shfl_xor(mx, 16));
        mx = fmaxf(mx, __shfl_xor(mx, 32));

        bool need = mx > mrun + 8.f;       // defer-max (T13)
        if (__ballot(need)) {
            float mnew = fmaxf(mrun, mx);
            float rf = exp2f(mrun - mnew);
            mrun = mnew;
#pragma unroll
            for (int r = 0; r < 4; r++) ls[r] *= rf;
#pragma unroll
            for (int nt = 0; nt < 4; nt++)
#pragma unroll
                for (int r = 0; r < 4; r++) o[nt][r] *= rf;
        }
#pragma unroll
        for (int t2 = 0; t2 < 4; t2++)
#pragma unroll
            for (int r = 0; r < 4; r++) st[t2][r] = exp2f(st[t2][r] - mrun);

        // shuffle-free P -> B-operand (V^T columns pre-permuted to match):
        // pbf[ks] slot j = st[2ks+(j>>2)][j&3]
        bf16x8 pbf[2];
#pragma unroll
        for (int ks = 0; ks < 2; ++ks) {
            i32x4 vv;
            vv[0] = (int)cvtpk_bf16(st[2 * ks][0], st[2 * ks][1]);
            vv[1] = (int)cvtpk_bf16(st[2 * ks][2], st[2 * ks][3]);
            vv[2] = (int)cvtpk_bf16(st[2 * ks + 1][0], st[2 * ks + 1][1]);
            vv[3] = (int)cvtpk_bf16(st[2 * ks + 1][2], st[2 * ks + 1][3]);
            pbf[ks] = __builtin_bit_cast(bf16x8, vv);
        }

        // O^T += V^T @ P^T ; ls += ones @ P^T (full 64-position row-sum)
        __builtin_amdgcn_s_setprio(1);
#pragma unroll
        for (int ks = 0; ks < 2; ++ks) {
            ls = __builtin_amdgcn_mfma_f32_16x16x32_bf16(onesf, pbf[ks], ls, 0, 0, 0);
#pragma unroll
            for (int nt = 0; nt < 4; nt++) {
                int vrow = nt * 16 + c;
                int vch = (ks * 4 + g) ^ (vrow & 7);
                bf16x8 vb = *(const bf16x8*)&Vsm[pbuf][vrow * 64 + vch * 8];
                o[nt] = __builtin_amdgcn_mfma_f32_16x16x32_bf16(vb, pbf[ks], o[nt], 0, 0, 0);
            }
        }
        __builtin_amdgcn_s_setprio(0);
        __builtin_amdgcn_s_barrier();      // all waves done reading buf[pbuf]
    }

    long prow = (long)(chunk * 32 + p_) * 512 + qb0 + w * 16;
#pragma unroll
    for (int nt = 0; nt < 4; nt++)
        *(f32x4*)&Op[(prow + c) * 64 + nt * 16 + g * 4] = o[nt];
    if (g == 0) ML[prow + c] = make_float2(mrun, ls[0]);
}

// ---------------- combine: merge 8 kv-chunk partials ----------------
__global__ __launch_bounds__(256) void attn_combine(const float* __restrict__ Op,
                                                    const float2* __restrict__ ML,
                                                    u16* __restrict__ O) {
    int tid = threadIdx.x;
    int w = tid >> 6, l = tid & 63;
    long rid = (long)blockIdx.x * 4 + w;   // 0..16383 : (p_, row)
    int p_ = (int)(rid >> 9);
    int row = (int)(rid & 511);
    int b = p_ >> 3, h = p_ & 7;
    float2 m[8];
#pragma unroll
    for (int cc = 0; cc < 8; cc++) m[cc] = ML[((long)(cc * 32 + p_) * 512 + row)];
    float mstar = fmaxf(fmaxf(fmaxf(m[0].x, m[1].x), fmaxf(m[2].x, m[3].x)),
                        fmaxf(fmaxf(m[4].x, m[5].x), fmaxf(m[6].x, m[7].x)));
    float wsum = 0.f, acc = 0.f;
#pragma unroll
    for (int cc = 0; cc < 8; cc++) {
        float wgt = exp2f(m[cc].x - mstar);
        wsum += wgt * m[cc].y;
        acc += wgt * Op[((long)(cc * 32 + p_) * 512 + row) * 64 + l];
    }
    O[((long)(b * 512 + row)) * 512 + h * 64 + l] = f2bf(acc / wsum);
}

// ---------------- launch ----------------

extern "C" void kernel_launch(void* const* d_in, const int* in_sizes, int n_in,
                              void* d_out, int out_size, void* d_ws, size_t ws_size,
                              hipStream_t stream) {
    const float* x = (const float*)d_in[0];
    const float* ctx = (const float*)d_in[1];
    const float* Wq = (const float*)d_in[2];
    const float* Wkv = (const float*)d_in[3];
    const float* Wout = (const float*)d_in[4];
    float* out = (float*)d_out;

    char* ws = (char*)d_ws;
    size_t off = 0;
    auto alloc = [&](size_t bytes) {
        size_t r = off;
        off += (bytes + 255) & ~(size_t)255;
        return r;
    };
    u16* ctxb = (u16*)(ws + alloc(4L * 4608 * 512 * 2));
    u16* wqb = (u16*)(ws + alloc(512L * 512 * 2));
    u16* wkvb = (u16*)(ws + alloc(1024L * 512 * 2));
    u16* woutb = (u16*)(ws + alloc(512L * 512 * 2));
    u16* qb = (u16*)(ws + alloc(2048L * 512 * 2));
    u16* kb = (u16*)(ws + alloc(4L * 4608 * 512 * 2));
    u16* vtb = (u16*)(ws + alloc(4L * 8 * 64 * 4608 * 2));
    u16* aob = (u16*)(ws + alloc(2048L * 512 * 2));
    float* opb = (float*)(ws + alloc(8L * 32 * 512 * 64 * 4));   // 33.6 MB
    float2* mlb = (float2*)(ws + alloc(8L * 32 * 512 * 8));      // 1 MB

    prep_all<<<dim3(5120), dim3(256), 0, stream>>>(x, ctx, Wq, Wkv, Wout,
                                                   ctxb, wqb, wkvb, woutb);
    // kv projection (by 0..143, bx 0..7) + q projection (by 144..159, bx<4)
    gemm_kvq<<<dim3(8, 160), dim3(512), 0, stream>>>(ctxb, wkvb, wqb, kb, vtb, qb);
    attn_kern<<<dim3(1024), dim3(512), 0, stream>>>(qb, kb, vtb, opb, mlb);
    attn_combine<<<dim3(4096), dim3(256), 0, stream>>>(opb, mlb, aob);
    gemm_out<<<dim3(4, 32), dim3(256), 0, stream>>>(aob, woutb, out);
}

// Round 10
// 167.511 us; speedup vs baseline: 1.1479x; 1.0420x over previous
//
#include <hip/hip_runtime.h>
#include <hip/hip_bf16.h>
#include <cstdint>

#define DEVI __device__ __forceinline__

typedef unsigned short u16;
typedef unsigned int u32;
typedef __attribute__((ext_vector_type(8))) short bf16x8;
typedef __attribute__((ext_vector_type(4))) float f32x4;
typedef __attribute__((ext_vector_type(4))) int i32x4;

DEVI u16 f2bf(float f) {
    union { float f; u32 u; } v; v.f = f;
    u32 r = v.u + 0x7fffu + ((v.u >> 16) & 1u);
    return (u16)(r >> 16);
}
DEVI u32 pk2(float a, float b) { return (u32)f2bf(a) | ((u32)f2bf(b) << 16); }

DEVI u32 cvtpk_bf16(float lo, float hi) {
    u32 r;
    asm("v_cvt_pk_bf16_f32 %0, %1, %2" : "=v"(r) : "v"(lo), "v"(hi));
    return r;
}

DEVI float bf2f(u16 v) {
    union { u32 u; float f; } x; x.u = (u32)v << 16;
    return x.f;
}

DEVI void gload_lds16(const void* g, void* l) {
    __builtin_amdgcn_global_load_lds(
        (const __attribute__((address_space(1))) u32*)(uintptr_t)g,
        (__attribute__((address_space(3))) u32*)(u32)(uintptr_t)l,
        16, 0, 0);
}

// ---------------- fused prep: build ctxb + cast 3 weight mats ----------------
// Wq is pre-scaled by 0.125*log2(e) so attention scores land in exp2 domain.
__global__ __launch_bounds__(256) void prep_all(const float* __restrict__ x,
                                                const float* __restrict__ ctx,
                                                const float* __restrict__ Wq,
                                                const float* __restrict__ Wkv,
                                                const float* __restrict__ Wout,
                                                u16* __restrict__ ctxb,
                                                u16* __restrict__ wqb,
                                                u16* __restrict__ wkvb,
                                                u16* __restrict__ woutb) {
    int id = blockIdx.x;
    int tid = threadIdx.x;
    if (id < 4608) {                       // ctxb build
        int idx = id * 256 + tid;
        long e0 = (long)idx * 8;
        int b = (int)(e0 / (4608L * 512));
        long rem = e0 % (4608L * 512);
        int m = (int)(rem / 512);
        int d = (int)(rem % 512);
        const float* src = (m < 512) ? (x + ((long)b * 512 + m) * 512 + d)
                                     : (ctx + ((long)b * 4096 + (m - 512)) * 512 + d);
        float4 a = *(const float4*)src;
        float4 c = *(const float4*)(src + 4);
        uint4 u;
        u.x = pk2(a.x, a.y); u.y = pk2(a.z, a.w);
        u.z = pk2(c.x, c.y); u.w = pk2(c.z, c.w);
        *(uint4*)&ctxb[e0] = u;
        return;
    }
    const float* s;
    u16* d;
    int i;
    float scl = 1.0f;
    if (id < 4736)      { s = Wq;   d = wqb;   i = (id - 4608) * 256 + tid;
                          scl = 0.125f * 1.44269504f; }
    else if (id < 4992) { s = Wkv;  d = wkvb;  i = (id - 4736) * 256 + tid; }
    else                { s = Wout; d = woutb; i = (id - 4992) * 256 + tid; }
    const float4* s4 = (const float4*)s;
    float4 a = s4[i * 2], b = s4[i * 2 + 1];
    uint4 u;
    u.x = pk2(a.x * scl, a.y * scl); u.y = pk2(a.z * scl, a.w * scl);
    u.z = pk2(b.x * scl, b.y * scl); u.w = pk2(b.z * scl, b.w * scl);
    ((uint4*)d)[i] = u;
}

// ---------------- big GEMM: 128x128 tile, 8 waves (64x32 wave tile), BK=64, dbuf ----
// 64KB LDS -> 2 blocks/CU. by < 144: kv projection; by >= 144: q projection (bx<4).
// V^T per-64-block column permutation p = (mt>>1)*32 + g*8 + (mt&1)*4 + r.
__global__ __launch_bounds__(512) void gemm_kvq(const u16* __restrict__ ctxb,
                                                const u16* __restrict__ wkvb,
                                                const u16* __restrict__ wqb,
                                                u16* __restrict__ kb,
                                                u16* __restrict__ vtb,
                                                u16* __restrict__ qb) {
    const int K = 512;
    __shared__ u16 Asm[2][128 * 64];   // 16KB x2
    __shared__ u16 Bsm[2][128 * 64];   // 16KB x2
    int tid = threadIdx.x;
    int w = tid >> 6, l = tid & 63;
    int g = l >> 4, c = l & 15;
    int wr = w >> 2, wc = w & 3;       // 2x4 wave grid: wave tile 64x32

    const u16* B;
    u16* C;
    long r0, arow0;
    bool isq = (blockIdx.y >= 144);
    if (isq) {
        if (blockIdx.x >= 4) return;
        r0 = (long)(blockIdx.y - 144) * 128;
        arow0 = (r0 / 512) * (4608L * 512) + (r0 % 512) * K;
        B = wqb;
        C = qb;
    } else {
        r0 = (long)blockIdx.y * 128;
        arow0 = (r0 / 4608) * (4608L * 512) + (r0 % 4608) * K;
        B = wkvb;
        C = kb;
    }
    int n0 = blockIdx.x * 128;

    f32x4 acc[4][2];
#pragma unroll
    for (int i = 0; i < 4; i++)
#pragma unroll
        for (int j = 0; j < 2; j++) acc[i][j] = (f32x4){0.f, 0.f, 0.f, 0.f};

    int srow = l >> 3;
    int sch = l & 7;

    auto stage = [&](int kt, int bb) {
#pragma unroll
        for (int i = 0; i < 2; i++) {       // A,B: 16 chunks each, 2/wave
            int c2 = w * 2 + i;
            int row = c2 * 8 + srow;
            int sc = sch ^ (row & 7);
            gload_lds16(ctxb + arow0 + (long)row * K + kt * 64 + sc * 8,
                        &Asm[bb][c2 * 512 + (l << 3)]);
            gload_lds16(B + (long)(n0 + row) * K + kt * 64 + sc * 8,
                        &Bsm[bb][c2 * 512 + (l << 3)]);
        }
    };

    stage(0, 0);
#pragma unroll 2
    for (int kt = 0; kt < 8; ++kt) {
        int pb = kt & 1;
        if (kt < 7) {
            stage(kt + 1, pb ^ 1);
            asm volatile("s_waitcnt vmcnt(4)" ::: "memory");
        } else {
            asm volatile("s_waitcnt vmcnt(0)" ::: "memory");
        }
        __builtin_amdgcn_s_barrier();
        __builtin_amdgcn_sched_barrier(0);
#pragma unroll
        for (int ks = 0; ks < 2; ++ks) {
            bf16x8 af[4], bfr[2];
#pragma unroll
            for (int mt = 0; mt < 4; ++mt) {
                int row = wr * 64 + mt * 16 + c;
                int ch = (ks * 4 + g) ^ (row & 7);
                af[mt] = *(const bf16x8*)&Asm[pb][row * 64 + ch * 8];
            }
#pragma unroll
            for (int nt = 0; nt < 2; ++nt) {
                int row = wc * 32 + nt * 16 + c;
                int ch = (ks * 4 + g) ^ (row & 7);
                bfr[nt] = *(const bf16x8*)&Bsm[pb][row * 64 + ch * 8];
            }
            __builtin_amdgcn_s_setprio(1);
#pragma unroll
            for (int mt = 0; mt < 4; ++mt)
#pragma unroll
                for (int nt = 0; nt < 2; ++nt)
                    acc[mt][nt] = __builtin_amdgcn_mfma_f32_16x16x32_bf16(
                        af[mt], bfr[nt], acc[mt][nt], 0, 0, 0);
            __builtin_amdgcn_s_setprio(0);
        }
        __builtin_amdgcn_s_barrier();
    }

    if (!isq && n0 >= 512) {               // V half -> VT[b,h,d,m'] permuted-transposed
        int b2 = (int)(r0 / 4608);
        int mb = (int)(r0 - (long)b2 * 4608) + wr * 64;   // multiple of 64
#pragma unroll
        for (int mt = 0; mt < 4; ++mt) {
#pragma unroll
            for (int nt = 0; nt < 2; ++nt) {
                int colv = (n0 - 512) + wc * 32 + nt * 16 + c;
                int hh = colv >> 6, dd = colv & 63;
                long ob = ((long)(b2 * 8 + hh) * 64 + dd) * 4608 + mb
                        + (mt >> 1) * 32 + g * 8 + (mt & 1) * 4;
                ushort4 pk;
                pk.x = f2bf(acc[mt][nt][0]);
                pk.y = f2bf(acc[mt][nt][1]);
                pk.z = f2bf(acc[mt][nt][2]);
                pk.w = f2bf(acc[mt][nt][3]);
                *(ushort4*)&vtb[ob] = pk;
            }
        }
        return;
    }
#pragma unroll
    for (int mt = 0; mt < 4; ++mt) {
#pragma unroll
        for (int r = 0; r < 4; ++r) {
            long row = r0 + wr * 64 + mt * 16 + g * 4 + r;
#pragma unroll
            for (int nt = 0; nt < 2; ++nt) {
                int col = n0 + wc * 32 + nt * 16 + c;
                C[row * 512 + col] = f2bf(acc[mt][nt][r]);
            }
        }
    }
}

// ---------------- out GEMM: 64x64 tile, 4 waves (32x32 wave tile), f32 out ----------------
__global__ __launch_bounds__(256) void gemm_out(const u16* __restrict__ A,
                                                const u16* __restrict__ B,
                                                float* __restrict__ C) {
    const int K = 512;
    __shared__ u16 Asm[2][64 * 64];
    __shared__ u16 Bsm[2][64 * 64];
    int tid = threadIdx.x;
    int w = tid >> 6, l = tid & 63;
    int g = l >> 4, c = l & 15;
    int wr = w >> 1, wc = w & 1;       // 2x2 wave grid over 64x64
    long r0 = (long)blockIdx.y * 64;
    long arow0 = r0 * K;
    int n0 = blockIdx.x * 64;

    f32x4 acc[2][2];
#pragma unroll
    for (int i = 0; i < 2; i++)
#pragma unroll
        for (int j = 0; j < 2; j++) acc[i][j] = (f32x4){0.f, 0.f, 0.f, 0.f};

    int srow = l >> 3;
    int sch = l & 7;

    auto stage = [&](int kt, int bb) {
#pragma unroll
        for (int i = 0; i < 2; i++) {       // A,B: 8 chunks each, 2/wave
            int c2 = w * 2 + i;
            int row = c2 * 8 + srow;
            int sc = sch ^ (row & 7);
            gload_lds16(A + arow0 + (long)row * K + kt * 64 + sc * 8,
                        &Asm[bb][c2 * 512 + (l << 3)]);
            gload_lds16(B + (long)(n0 + row) * K + kt * 64 + sc * 8,
                        &Bsm[bb][c2 * 512 + (l << 3)]);
        }
    };

    stage(0, 0);
#pragma unroll 2
    for (int kt = 0; kt < 8; ++kt) {
        int pb = kt & 1;
        if (kt < 7) {
            stage(kt + 1, pb ^ 1);
            asm volatile("s_waitcnt vmcnt(4)" ::: "memory");
        } else {
            asm volatile("s_waitcnt vmcnt(0)" ::: "memory");
        }
        __builtin_amdgcn_s_barrier();
        __builtin_amdgcn_sched_barrier(0);
#pragma unroll
        for (int ks = 0; ks < 2; ++ks) {
            bf16x8 af[2], bfr[2];
#pragma unroll
            for (int mt = 0; mt < 2; ++mt) {
                int row = wr * 32 + mt * 16 + c;
                int ch = (ks * 4 + g) ^ (row & 7);
                af[mt] = *(const bf16x8*)&Asm[pb][row * 64 + ch * 8];
            }
#pragma unroll
            for (int nt = 0; nt < 2; ++nt) {
                int row = wc * 32 + nt * 16 + c;
                int ch = (ks * 4 + g) ^ (row & 7);
                bfr[nt] = *(const bf16x8*)&Bsm[pb][row * 64 + ch * 8];
            }
#pragma unroll
            for (int mt = 0; mt < 2; ++mt)
#pragma unroll
                for (int nt = 0; nt < 2; ++nt)
                    acc[mt][nt] = __builtin_amdgcn_mfma_f32_16x16x32_bf16(
                        af[mt], bfr[nt], acc[mt][nt], 0, 0, 0);
        }
        __builtin_amdgcn_s_barrier();
    }
#pragma unroll
    for (int mt = 0; mt < 2; ++mt) {
#pragma unroll
        for (int r = 0; r < 4; ++r) {
            long row = r0 + wr * 32 + mt * 16 + g * 4 + r;
#pragma unroll
            for (int nt = 0; nt < 2; ++nt) {
                int col = n0 + wc * 32 + nt * 16 + c;
                C[row * 512 + col] = acc[mt][nt][r];
            }
        }
    }
}

// ---------------- flash attention: 8 waves/block, split-KV x4, shuffle-free P ----------------
// 512 blocks = 128 units (b,h,chunk) x 4 qblocks(128 q) = exactly 2 blocks/CU.
// S^T = mfma(K,Q) (Q pre-scaled to exp2 domain); softmax in-lane; P regrouped
// in-lane to PV B-operand (V^T pre-permuted). Row-sum via ones-MFMA.
// Partials written in bf16 (halves Op round-trip traffic).
__global__ __launch_bounds__(512) void attn_kern(const u16* __restrict__ Q,
                                                 const u16* __restrict__ KB,
                                                 const u16* __restrict__ VT,
                                                 u16* __restrict__ Op,
                                                 float2* __restrict__ ML) {
    __shared__ u16 Ksm[2][64 * 64];
    __shared__ u16 Vsm[2][64 * 64];
    int tid = threadIdx.x;
    int w = tid >> 6, l = tid & 63;
    int g = l >> 4, c = l & 15;
    int id = blockIdx.x;
    int u = (id & 7) | ((id >> 5) << 3);   // unit (b,h,chunk) 0..127
    int qi = (id >> 3) & 3;
    int p_ = u >> 2, chunk = u & 3;
    int b = p_ >> 3, h = p_ & 7;
    int qb0 = qi * 128;
    const int NT = 18;
    int it0 = chunk * NT;

    bf16x8 qf[2];   // B-operand fragment: Q^T[d=ks*32+g*8+j][q=c]
    {
        long qrow = (long)(b * 512 + qb0 + w * 16 + c);
#pragma unroll
        for (int ks = 0; ks < 2; ++ks)
            qf[ks] = *(const bf16x8*)&Q[qrow * 512 + h * 64 + ks * 32 + g * 8];
    }
    bf16x8 onesf;
#pragma unroll
    for (int e = 0; e < 8; e++) onesf[e] = (short)0x3F80;  // bf16 1.0

    f32x4 o[4];     // O^T[d=nt*16+g*4+r][q=c]
#pragma unroll
    for (int nt = 0; nt < 4; nt++) o[nt] = (f32x4){0.f, 0.f, 0.f, 0.f};
    f32x4 ls = (f32x4){0.f, 0.f, 0.f, 0.f};   // row-sum accum
    float mrun = -1e30f;

    const long kbase = (long)b * 4608 * 512 + h * 64;
    const long vtbase = (long)(b * 8 + h) * 64 * 4608;

    int srow = tid >> 3;               // staging: this thread's tile row
    int ssc = (tid & 7) ^ (srow & 7);  // pre-swizzled source chunk

    auto stage = [&](int it, int bb) {
        gload_lds16(KB + kbase + (long)(it * 64 + srow) * 512 + ssc * 8,
                    &Ksm[bb][tid * 8]);
        gload_lds16(VT + vtbase + (long)srow * 4608 + it * 64 + ssc * 8,
                    &Vsm[bb][tid * 8]);
    };

    stage(it0, 0);
    for (int t = 0; t < NT; ++t) {
        int pbuf = t & 1;
        if (t + 1 < NT) {
            stage(it0 + t + 1, pbuf ^ 1);
            asm volatile("s_waitcnt vmcnt(2)" ::: "memory");
        } else {
            asm volatile("s_waitcnt vmcnt(0)" ::: "memory");
        }
        __builtin_amdgcn_s_barrier();      // tile t resident everywhere
        __builtin_amdgcn_sched_barrier(0);

        // S^T = K @ Q^T (already in exp2 domain)
        f32x4 st[4];
#pragma unroll
        for (int t2 = 0; t2 < 4; t2++) st[t2] = (f32x4){0.f, 0.f, 0.f, 0.f};
        __builtin_amdgcn_s_setprio(1);
#pragma unroll
        for (int ks = 0; ks < 2; ++ks) {
#pragma unroll
            for (int t2 = 0; t2 < 4; t2++) {
                int row = t2 * 16 + c;
                int ch = (ks * 4 + g) ^ (row & 7);
                bf16x8 kf = *(const bf16x8*)&Ksm[pbuf][row * 64 + ch * 8];
                st[t2] = __builtin_amdgcn_mfma_f32_16x16x32_bf16(kf, qf[ks], st[t2], 0, 0, 0);
            }
        }
        __builtin_amdgcn_s_setprio(0);

        float mx01 = fmaxf(fmaxf(st[0][0], st[0][1]), fmaxf(st[0][2], st[0][3]));
        float mx23 = fmaxf(fmaxf(st[1][0], st[1][1]), fmaxf(st[1][2], st[1][3]));
        float mx45 = fmaxf(fmaxf(st[2][0], st[2][1]), fmaxf(st[2][2], st[2][3]));
        float mx67 = fmaxf(fmaxf(st[3][0], st[3][1]), fmaxf(st[3][2], st[3][3]));
        float mx = fmaxf(fmaxf(mx01, mx23), fmaxf(mx45, mx67));
        mx = fmaxf(mx, __shfl_xor(mx, 16));
        mx = fmaxf(mx, __shfl_xor(mx, 32));

        bool need = mx > mrun + 8.f;       // defer-max (T13)
        if (__ballot(need)) {
            float mnew = fmaxf(mrun, mx);
            float rf = exp2f(mrun - mnew);
            mrun = mnew;
#pragma unroll
            for (int r = 0; r < 4; r++) ls[r] *= rf;
#pragma unroll
            for (int nt = 0; nt < 4; nt++)
#pragma unroll
                for (int r = 0; r < 4; r++) o[nt][r] *= rf;
        }
#pragma unroll
        for (int t2 = 0; t2 < 4; t2++)
#pragma unroll
            for (int r = 0; r < 4; r++) st[t2][r] = exp2f(st[t2][r] - mrun);

        // shuffle-free P -> B-operand (V^T columns pre-permuted to match):
        bf16x8 pbf[2];
#pragma unroll
        for (int ks = 0; ks < 2; ++ks) {
            i32x4 vv;
            vv[0] = (int)cvtpk_bf16(st[2 * ks][0], st[2 * ks][1]);
            vv[1] = (int)cvtpk_bf16(st[2 * ks][2], st[2 * ks][3]);
            vv[2] = (int)cvtpk_bf16(st[2 * ks + 1][0], st[2 * ks + 1][1]);
            vv[3] = (int)cvtpk_bf16(st[2 * ks + 1][2], st[2 * ks + 1][3]);
            pbf[ks] = __builtin_bit_cast(bf16x8, vv);
        }

        // O^T += V^T @ P^T ; ls += ones @ P^T (full 64-position row-sum)
        __builtin_amdgcn_s_setprio(1);
#pragma unroll
        for (int ks = 0; ks < 2; ++ks) {
            ls = __builtin_amdgcn_mfma_f32_16x16x32_bf16(onesf, pbf[ks], ls, 0, 0, 0);
#pragma unroll
            for (int nt = 0; nt < 4; nt++) {
                int vrow = nt * 16 + c;
                int vch = (ks * 4 + g) ^ (vrow & 7);
                bf16x8 vb = *(const bf16x8*)&Vsm[pbuf][vrow * 64 + vch * 8];
                o[nt] = __builtin_amdgcn_mfma_f32_16x16x32_bf16(vb, pbf[ks], o[nt], 0, 0, 0);
            }
        }
        __builtin_amdgcn_s_setprio(0);
        __builtin_amdgcn_s_barrier();      // all waves done reading buf[pbuf]
    }

    long prow = (long)(chunk * 32 + p_) * 512 + qb0 + w * 16;
#pragma unroll
    for (int nt = 0; nt < 4; nt++) {
        uint2 pk;
        pk.x = cvtpk_bf16(o[nt][0], o[nt][1]);
        pk.y = cvtpk_bf16(o[nt][2], o[nt][3]);
        *(uint2*)&Op[(prow + c) * 64 + nt * 16 + g * 4] = pk;
    }
    if (g == 0) ML[prow + c] = make_float2(mrun, ls[0]);
}

// ---------------- combine: merge 4 kv-chunk partials (bf16 Op) ----------------
__global__ __launch_bounds__(256) void attn_combine(const u16* __restrict__ Op,
                                                    const float2* __restrict__ ML,
                                                    u16* __restrict__ O) {
    int tid = threadIdx.x;
    int w = tid >> 6, l = tid & 63;
    long rid = (long)blockIdx.x * 4 + w;   // 0..16383 : (p_, row)
    int p_ = (int)(rid >> 9);
    int row = (int)(rid & 511);
    int b = p_ >> 3, h = p_ & 7;
    float2 m[4];
#pragma unroll
    for (int cc = 0; cc < 4; cc++) m[cc] = ML[((long)(cc * 32 + p_) * 512 + row)];
    float mstar = fmaxf(fmaxf(m[0].x, m[1].x), fmaxf(m[2].x, m[3].x));
    float wsum = 0.f, acc = 0.f;
#pragma unroll
    for (int cc = 0; cc < 4; cc++) {
        float wgt = exp2f(m[cc].x - mstar);
        wsum += wgt * m[cc].y;
        acc += wgt * bf2f(Op[((long)(cc * 32 + p_) * 512 + row) * 64 + l]);
    }
    O[((long)(b * 512 + row)) * 512 + h * 64 + l] = f2bf(acc / wsum);
}

// ---------------- launch ----------------

extern "C" void kernel_launch(void* const* d_in, const int* in_sizes, int n_in,
                              void* d_out, int out_size, void* d_ws, size_t ws_size,
                              hipStream_t stream) {
    const float* x = (const float*)d_in[0];
    const float* ctx = (const float*)d_in[1];
    const float* Wq = (const float*)d_in[2];
    const float* Wkv = (const float*)d_in[3];
    const float* Wout = (const float*)d_in[4];
    float* out = (float*)d_out;

    char* ws = (char*)d_ws;
    size_t off = 0;
    auto alloc = [&](size_t bytes) {
        size_t r = off;
        off += (bytes + 255) & ~(size_t)255;
        return r;
    };
    u16* ctxb = (u16*)(ws + alloc(4L * 4608 * 512 * 2));
    u16* wqb = (u16*)(ws + alloc(512L * 512 * 2));
    u16* wkvb = (u16*)(ws + alloc(1024L * 512 * 2));
    u16* woutb = (u16*)(ws + alloc(512L * 512 * 2));
    u16* qb = (u16*)(ws + alloc(2048L * 512 * 2));
    u16* kb = (u16*)(ws + alloc(4L * 4608 * 512 * 2));
    u16* vtb = (u16*)(ws + alloc(4L * 8 * 64 * 4608 * 2));
    u16* aob = (u16*)(ws + alloc(2048L * 512 * 2));
    u16* opb = (u16*)(ws + alloc(4L * 32 * 512 * 64 * 2));       // 8.4 MB (bf16)
    float2* mlb = (float2*)(ws + alloc(4L * 32 * 512 * 8));      // 0.5 MB

    prep_all<<<dim3(5120), dim3(256), 0, stream>>>(x, ctx, Wq, Wkv, Wout,
                                                   ctxb, wqb, wkvb, woutb);
    // kv projection (by 0..143, bx 0..7) + q projection (by 144..159, bx<4)
    gemm_kvq<<<dim3(8, 160), dim3(512), 0, stream>>>(ctxb, wkvb, wqb, kb, vtb, qb);
    attn_kern<<<dim3(512), dim3(512), 0, stream>>>(qb, kb, vtb, opb, mlb);
    attn_combine<<<dim3(4096), dim3(256), 0, stream>>>(opb, mlb, aob);
    gemm_out<<<dim3(8, 32), dim3(256), 0, stream>>>(aob, woutb, out);
}